// Round 1
// baseline (906.691 us; speedup 1.0000x reference)
//
#include <hip/hip_runtime.h>
#include <cstddef>

#define DD 128
#define FAN 8

__device__ __forceinline__ void lds_fence() {
    asm volatile("s_waitcnt lgkmcnt(0)" ::: "memory");
}

// Fused SAGE layer: for each dst row r:
//   neigh = mean_{j<8} X[es[8r+j]]
//   Y[r]  = X[r] @ Ws + neigh @ Wn + bn   (optional relu)
// Weights [Ws;Wn] (256x128 f32 = 128 KB) stationary in LDS; 8 waves/block,
// each wave owns R rows per group; lane computes 2 output columns.
template<bool RELU, int R>
__global__ __launch_bounds__(512, 2)
void sage_kernel(const float* __restrict__ X, const int* __restrict__ es,
                 const float* __restrict__ Ws, const float* __restrict__ Wn,
                 const float* __restrict__ bn, float* __restrict__ Y,
                 int n_dst, int n_groups)
{
    __shared__ float sW[2 * DD][DD];     // 128 KB: rows 0..127 Ws, 128..255 Wn
    __shared__ float sx[8][R][2 * DD];   // per-wave [self|neigh] rows

    const int tid  = threadIdx.x;
    const int lane = tid & 63;
    const int wave = tid >> 6;

    // cooperative W load (32768 floats = 8192 float4)
    {
        const float4* s0 = (const float4*)Ws;
        const float4* s1 = (const float4*)Wn;
        float4* dst = (float4*)&sW[0][0];
        #pragma unroll
        for (int i = 0; i < 8; ++i) dst[tid + 512 * i] = s0[tid + 512 * i];
        #pragma unroll
        for (int i = 0; i < 8; ++i) dst[4096 + tid + 512 * i] = s1[tid + 512 * i];
    }
    __syncthreads();

    const float2 bv = *((const float2*)bn + lane);

    for (int g = blockIdx.x; g < n_groups; g += gridDim.x) {
        const int row0 = g * (8 * R) + wave * R;

        // ---- gather + mean + stage x = [self | neigh] into LDS ----
        #pragma unroll
        for (int rr = 0; rr < R; ++rr) {
            const int r = row0 + rr;
            if (r >= n_dst) continue;
            const int* ep = es + (size_t)r * FAN;
            float a0 = 0.f, a1 = 0.f;
            #pragma unroll
            for (int j = 0; j < FAN; ++j) {
                const int sj = ep[j];
                const float2 v = *((const float2*)(X + (size_t)sj * DD) + lane);
                a0 += v.x; a1 += v.y;
            }
            const float2 sv = *((const float2*)(X + (size_t)r * DD) + lane);
            *(float2*)&sx[wave][rr][2 * lane] = sv;
            *(float2*)&sx[wave][rr][DD + 2 * lane] = make_float2(a0 * 0.125f, a1 * 0.125f);
        }
        lds_fence();

        // ---- K=256 inner product; W reads amortized over R rows ----
        float2 acc[R];
        #pragma unroll
        for (int rr = 0; rr < R; ++rr) acc[rr] = make_float2(0.f, 0.f);

        #pragma unroll 8
        for (int k = 0; k < 2 * DD; k += 2) {
            const float2 w0 = *((const float2*)&sW[k][0]     + lane);
            const float2 w1 = *((const float2*)&sW[k + 1][0] + lane);
            #pragma unroll
            for (int rr = 0; rr < R; ++rr) {
                const float2 xv = *(const float2*)&sx[wave][rr][k];
                acc[rr].x = fmaf(xv.x, w0.x, acc[rr].x);
                acc[rr].y = fmaf(xv.x, w0.y, acc[rr].y);
                acc[rr].x = fmaf(xv.y, w1.x, acc[rr].x);
                acc[rr].y = fmaf(xv.y, w1.y, acc[rr].y);
            }
        }

        // ---- epilogue ----
        #pragma unroll
        for (int rr = 0; rr < R; ++rr) {
            const int r = row0 + rr;
            if (r >= n_dst) continue;
            float o0 = acc[rr].x + bv.x;
            float o1 = acc[rr].y + bv.y;
            if (RELU) { o0 = fmaxf(o0, 0.f); o1 = fmaxf(o1, 0.f); }
            *((float2*)(Y + (size_t)r * DD) + lane) = make_float2(o0, o1);
        }
        lds_fence();
    }
}

// Fused predictor: rows 0..511 -> pos, 512..1023 -> neg.
// x = src*other; t1 = relu(x@W1+b1); t2 = relu(t1@W2+b2); out = t2@W3 + b3
__global__ __launch_bounds__(512, 2)
void pred_kernel(const float* __restrict__ h3,
                 const float* __restrict__ W1, const float* __restrict__ b1,
                 const float* __restrict__ W2, const float* __restrict__ b2,
                 const float* __restrict__ W3, const float* __restrict__ b3,
                 float* __restrict__ out)
{
    __shared__ float sW1[DD][DD];
    __shared__ float sW2[DD][DD];
    __shared__ float sW3[DD];
    __shared__ float sx[8][4][DD];

    const int tid = threadIdx.x, lane = tid & 63, wave = tid >> 6;
    {
        const float4* a = (const float4*)W1;  float4* d1 = (float4*)&sW1[0][0];
        const float4* c = (const float4*)W2;  float4* d2 = (float4*)&sW2[0][0];
        #pragma unroll
        for (int i = 0; i < 8; ++i) d1[tid + 512 * i] = a[tid + 512 * i];
        #pragma unroll
        for (int i = 0; i < 8; ++i) d2[tid + 512 * i] = c[tid + 512 * i];
        if (tid < DD) sW3[tid] = W3[tid];
    }
    __syncthreads();

    const int row0 = blockIdx.x * 32 + wave * 4;   // 32 blocks * 32 rows = 1024

    // x = src * (pos|neg)
    #pragma unroll
    for (int rr = 0; rr < 4; ++rr) {
        const int row = row0 + rr;
        const int i = row & 511;
        const int which = row >> 9;                // 0 = pos, 1 = neg
        const float2 a = *((const float2*)(h3 + (size_t)i * DD) + lane);
        const float2 c = *((const float2*)(h3 + (size_t)(512 + which * 512 + i) * DD) + lane);
        *(float2*)&sx[wave][rr][2 * lane] = make_float2(a.x * c.x, a.y * c.y);
    }
    lds_fence();

    // layer 1
    float2 t[4];
    #pragma unroll
    for (int rr = 0; rr < 4; ++rr) t[rr] = make_float2(0.f, 0.f);
    #pragma unroll 8
    for (int k = 0; k < DD; k += 2) {
        const float2 w0 = *((const float2*)&sW1[k][0]     + lane);
        const float2 w1 = *((const float2*)&sW1[k + 1][0] + lane);
        #pragma unroll
        for (int rr = 0; rr < 4; ++rr) {
            const float2 xv = *(const float2*)&sx[wave][rr][k];
            t[rr].x = fmaf(xv.x, w0.x, t[rr].x);
            t[rr].y = fmaf(xv.x, w0.y, t[rr].y);
            t[rr].x = fmaf(xv.y, w1.x, t[rr].x);
            t[rr].y = fmaf(xv.y, w1.y, t[rr].y);
        }
    }
    const float2 b1v = *((const float2*)b1 + lane);
    lds_fence();
    #pragma unroll
    for (int rr = 0; rr < 4; ++rr) {
        const float u0 = fmaxf(t[rr].x + b1v.x, 0.f);
        const float u1 = fmaxf(t[rr].y + b1v.y, 0.f);
        *(float2*)&sx[wave][rr][2 * lane] = make_float2(u0, u1);
    }
    lds_fence();

    // layer 2
    #pragma unroll
    for (int rr = 0; rr < 4; ++rr) t[rr] = make_float2(0.f, 0.f);
    #pragma unroll 8
    for (int k = 0; k < DD; k += 2) {
        const float2 w0 = *((const float2*)&sW2[k][0]     + lane);
        const float2 w1 = *((const float2*)&sW2[k + 1][0] + lane);
        #pragma unroll
        for (int rr = 0; rr < 4; ++rr) {
            const float2 xv = *(const float2*)&sx[wave][rr][k];
            t[rr].x = fmaf(xv.x, w0.x, t[rr].x);
            t[rr].y = fmaf(xv.x, w0.y, t[rr].y);
            t[rr].x = fmaf(xv.y, w1.x, t[rr].x);
            t[rr].y = fmaf(xv.y, w1.y, t[rr].y);
        }
    }
    const float2 b2v = *((const float2*)b2 + lane);
    const float bias3 = b3[0];

    // layer 3: dot with W3 (128x1), wave-reduce over 64 lanes
    #pragma unroll
    for (int rr = 0; rr < 4; ++rr) {
        const float u0 = fmaxf(t[rr].x + b2v.x, 0.f);
        const float u1 = fmaxf(t[rr].y + b2v.y, 0.f);
        float p = u0 * sW3[2 * lane] + u1 * sW3[2 * lane + 1];
        #pragma unroll
        for (int off = 32; off > 0; off >>= 1) p += __shfl_down(p, off);
        if (lane == 0) out[row0 + rr] = p + bias3;
    }
}

extern "C" void kernel_launch(void* const* d_in, const int* in_sizes, int n_in,
                              void* d_out, int out_size, void* d_ws, size_t ws_size,
                              hipStream_t stream)
{
    const float* h   = (const float*)d_in[0];
    const int*   es0 = (const int*)d_in[1];
    const int*   es1 = (const int*)d_in[2];
    const int*   es2 = (const int*)d_in[3];
    const float* Ws0 = (const float*)d_in[4];
    const float* Wn0 = (const float*)d_in[5];
    const float* bn0 = (const float*)d_in[6];
    const float* Ws1 = (const float*)d_in[7];
    const float* Wn1 = (const float*)d_in[8];
    const float* bn1 = (const float*)d_in[9];
    const float* Ws2 = (const float*)d_in[10];
    const float* Wn2 = (const float*)d_in[11];
    const float* bn2 = (const float*)d_in[12];
    const float* pW1 = (const float*)d_in[13];
    const float* pb1 = (const float*)d_in[14];
    const float* pW2 = (const float*)d_in[15];
    const float* pb2 = (const float*)d_in[16];
    const float* pW3 = (const float*)d_in[17];
    const float* pb3 = (const float*)d_in[18];
    float* out = (float*)d_out;

    char* ws = (char*)d_ws;
    float* h1 = (float*)(ws);                          // 124416*128*4 = 63,700,992 B
    float* h2 = (float*)(ws + 63700992);               // 13824*128*4  =  7,077,888 B
    float* h3 = (float*)(ws + 63700992 + 7077888);     // 1536*128*4   =    786,432 B

    // groups of 24 rows (8 waves * R=3); all layer sizes divide exactly
    sage_kernel<true, 3><<<512, 512, 0, stream>>>(h,  es0, Ws0, Wn0, bn0, h1, 124416, 5184);
    sage_kernel<true, 3><<<512, 512, 0, stream>>>(h1, es1, Ws1, Wn1, bn1, h2, 13824, 576);
    sage_kernel<false,3><<<64,  512, 0, stream>>>(h2, es2, Ws2, Wn2, bn2, h3, 1536, 64);
    pred_kernel<<<32, 512, 0, stream>>>(h3, pW1, pb1, pW2, pb2, pW3, pb3, out);
}